// Round 15
// baseline (2085.588 us; speedup 1.0000x reference)
//
#include <hip/hip_runtime.h>
#include <stdint.h>

#define TT 1024
#define HB 256
#define O1 67108864u                // B*T*H
#define O2 (67108864u + 524288u)    // + B*T*2

typedef __attribute__((ext_vector_type(8))) short short8v;   // 8 bf16 (4 VGPR)
typedef __attribute__((ext_vector_type(4))) float float4v;

__device__ __forceinline__ uint32_t rotl32(uint32_t x, uint32_t r){ return (x<<r)|(x>>(32u-r)); }

#define RND(r) { x0+=x1; x1=rotl32(x1,(r)); x1^=x0; }
__device__ __forceinline__ void tf2x32(uint32_t k0,uint32_t k1,uint32_t& x0,uint32_t& x1){
  const uint32_t ks2 = 0x1BD11BDAu ^ k0 ^ k1;
  x0 += k0; x1 += k1;
  RND(13) RND(15) RND(26) RND(6)  x0+=k1;  x1+=ks2+1u;
  RND(17) RND(29) RND(16) RND(24) x0+=ks2; x1+=k0+2u;
  RND(13) RND(15) RND(26) RND(6)  x0+=k0;  x1+=k1+3u;
  RND(17) RND(29) RND(16) RND(24) x0+=k1;  x1+=ks2+4u;
  RND(13) RND(15) RND(26) RND(6)  x0+=ks2; x1+=k0+5u;
}
#undef RND

// uniform(-0.99999994,1) -> sqrt(2)*erfinv (Giles poly, HW log) -> *0.05*0.5
__device__ __forceinline__ float bits_to_noise(uint32_t bits){
  float f = __uint_as_float((bits>>9) | 0x3F800000u) - 1.0f;
  const float lo = -0.99999994f;
  float x = fmaxf(fmaf(f, 1.99999994f, lo), lo);
  float m = (1.0f - x) * (1.0f + x);
  float w = -0.69314718056f * __log2f(m);
  float p;
  if (w < 5.0f){
    w -= 2.5f;
    p = 2.81022636e-08f;
    p = fmaf(p, w, 3.43273939e-07f);
    p = fmaf(p, w, -3.5233877e-06f);
    p = fmaf(p, w, -4.39150654e-06f);
    p = fmaf(p, w, 0.00021858087f);
    p = fmaf(p, w, -0.00125372503f);
    p = fmaf(p, w, -0.00417768164f);
    p = fmaf(p, w, 0.246640727f);
    p = fmaf(p, w, 1.50140941f);
  } else {
    w = __fsqrt_rn(w) - 3.0f;
    p = -0.000200214257f;
    p = fmaf(p, w, 0.000100950558f);
    p = fmaf(p, w, 0.00134934322f);
    p = fmaf(p, w, -0.00367342844f);
    p = fmaf(p, w, 0.00573950773f);
    p = fmaf(p, w, -0.0076224613f);
    p = fmaf(p, w, 0.00943887047f);
    p = fmaf(p, w, 1.00167406f);
    p = fmaf(p, w, 2.83297682f);
  }
  return 0.035355339059f * (p * x);
}

// full-GPU pregen: noise(t,b,j) -> hidden_list slot out[b][t][j] (overwritten by h later)
__global__ void noise_kernel(float* __restrict__ out){
  uint32_t i = blockIdx.x*256u + threadIdx.x;    // 0 .. 2^26-1
  uint32_t x0 = 0u, x1 = i;
  tf2x32(0u, 42u, x0, x1);
  float n = bits_to_noise(x0 ^ x1);
  uint32_t t = i >> 16, b = (i >> 8) & 255u, j = i & 255u;
  out[(uint64_t)(b*TT + t)*HB + j] = n;
}

__device__ __forceinline__ short f2bf(float x){            // f32 -> bf16 (RNE)
  uint32_t u = __float_as_uint(x);
  return (short)((u + 0x7FFFu + ((u>>16)&1u)) >> 16);
}

// self-tests: threefry vectors (thread 0) + MFMA A/B/C layout (whole wave, exact-in-bf16)
__global__ void check_kernel(float* out){
  const int l = threadIdx.x;
  if (l == 0){
    uint32_t a0=0u, a1=0u;                 tf2x32(0u,0u,a0,a1);
    uint32_t b0=0xffffffffu, b1=0xffffffffu; tf2x32(0xffffffffu,0xffffffffu,b0,b1);
    uint32_t c0=0x243f6a88u, c1=0x85a308d3u; tf2x32(0x13198a2eu,0x03707344u,c0,c1);
    if (!(a0==0x6b200159u && a1==0x99ba4efeu)) out[0] = 1e30f;
    if (!(b0==0x1cb996fcu && b1==0xbb002be7u)) out[1] = 2e30f;
    if (!(c0==0xc4923a9cu && c1==0x483df7a0u)) out[2] = 3e30f;
  }
  // assumed layouts: A: m=lane&15, k=(lane>>4)*8+e ; B: n=lane&15, k=(lane>>4)*8+e ;
  // D: col=lane&15, row=(lane>>4)*4+e  (guide §3, m89-verified C/D)
  const int m = l & 15, gk = l >> 4;
  short8v a, bf;
  #pragma unroll
  for (int e = 0; e < 8; ++e){
    int k = gk*8 + e;
    a[e]  = f2bf((float)(m+1) + (float)k*0.125f);          // A[m][k], exact in bf16
    bf[e] = f2bf((float)(k+1)*0.0625f + (float)m*0.25f);   // B[k][n=m], exact in bf16
  }
  float4v c = {0.f,0.f,0.f,0.f};
  float4v d = __builtin_amdgcn_mfma_f32_16x16x32_bf16(a, bf, c, 0, 0, 0);
  float dv[4] = {d[0], d[1], d[2], d[3]};
  bool bad = false;
  #pragma unroll
  for (int e = 0; e < 4; ++e){
    int row = gk*4 + e;
    float ex = 0.f;
    for (int k = 0; k < 32; ++k)
      ex += ((float)(row+1) + (float)k*0.125f) * ((float)(k+1)*0.0625f + (float)m*0.25f);
    if (dv[e] != ex) bad = true;                           // exact arithmetic -> ==
  }
  if (bad) out[7] = 8e30f;
}

// 16 blocks x 16 batches: dense W (bf16 A-frags in registers) x tanh(h) via MFMA
__launch_bounds__(512, 2)
__global__ void rnn_kernel(const float* __restrict__ input_signal, // [B,T,2]
                           const float* __restrict__ hidden0,      // [B,H]
                           const float* __restrict__ w_in,         // [H,2]
                           const float* __restrict__ w_out,        // [2,H]
                           const float* __restrict__ abs_w0,       // [H,H]
                           const float* __restrict__ w_sign,       // [H,H]
                           const float* __restrict__ is_con,       // [H,H]
                           float* out)                             // noise in, h/o out
{
  __shared__ __attribute__((aligned(16))) short th_lds[2][16][264]; // tanh bf16 [bi][r]
  __shared__ __attribute__((aligned(16))) float hst[2][16][264];    // h f32 stage [bi][r]
  __shared__ float x_lds[2][64][16][2];                             // x chunks
  __shared__ float opart[2][8][16][2];                              // outproj partials

  const int tid  = threadIdx.x;
  const int w    = tid >> 6, lane = tid & 63;
  const int bi   = lane & 15, g = lane >> 4;
  const int b0   = blockIdx.x * 16;
  const int w32  = w * 32;

  // ---- init: W -> bf16 A-fragments (registers, fixed all steps) ----
  short8v afr[2][8];
  #pragma unroll
  for (int tau = 0; tau < 2; ++tau){
    const int r = w32 + tau*16 + bi;                 // A row m = lane&15
    #pragma unroll
    for (int kt = 0; kt < 8; ++kt){
      const int kb = kt*32 + g*8;                    // A k-run = (lane>>4)*8
      const float* ap = abs_w0 + r*HB + kb;
      const float* sp = w_sign + r*HB + kb;
      const float* cp = is_con + r*HB + kb;
      short8v af;
      #pragma unroll
      for (int e = 0; e < 8; ++e){
        float wv = (cp[e] > 0.f) ? sp[e]*ap[e] : 0.f;
        af[e] = f2bf(wv);
      }
      afr[tau][kt] = af;
    }
  }

  // per-lane row constants + h0
  float wi0r[8], wi1r[8], wo0r[8], wo1r[8], hr[8];
  #pragma unroll
  for (int tau = 0; tau < 2; ++tau)
    #pragma unroll
    for (int e = 0; e < 4; ++e){
      const int r = w32 + tau*16 + g*4 + e;
      wi0r[tau*4+e] = w_in[r*2];   wi1r[tau*4+e] = w_in[r*2+1];
      wo0r[tau*4+e] = w_out[r];    wo1r[tau*4+e] = w_out[HB + r];
      hr[tau*4+e]   = hidden0[(b0+bi)*HB + r];
    }

  // th[0] = tanh(h0)
  #pragma unroll
  for (int tau = 0; tau < 2; ++tau){
    uint32_t pk0 = 0u, pk1 = 0u;
    #pragma unroll
    for (int e = 0; e < 4; ++e){
      float th = 1.0f - 2.0f/(__expf(2.0f*hr[tau*4+e]) + 1.0f);
      uint32_t bb = (uint32_t)(uint16_t)f2bf(th);
      if (e < 2) pk0 |= bb << (16*e); else pk1 |= bb << (16*(e-2));
    }
    *(uint2*)((char*)&th_lds[0][0][0] + bi*528 + (w32 + tau*16 + g*4)*2) = make_uint2(pk0, pk1);
  }

  // x chunk 0
  {
    const int xbi = tid >> 5, toff = (tid & 31)*2;
    float4 xv = *(const float4*)(input_signal + (uint64_t)(b0+xbi)*TT*2 + toff*2);
    x_lds[0][toff  ][xbi][0] = xv.x; x_lds[0][toff  ][xbi][1] = xv.y;
    x_lds[0][toff+1][xbi][0] = xv.z; x_lds[0][toff+1][xbi][1] = xv.w;
  }

  // noise prefetch: t=0 (A-set), t=1 (B-set)
  const float* nzb = out + (uint64_t)(b0+bi)*TT*HB;
  float4 nzA0 = *(const float4*)(nzb + 0*HB + w32 +      g*4);
  float4 nzA1 = *(const float4*)(nzb + 0*HB + w32 + 16 + g*4);
  float4 nzB0 = *(const float4*)(nzb + 1*HB + w32 +      g*4);
  float4 nzB1 = *(const float4*)(nzb + 1*HB + w32 + 16 + g*4);
  __syncthreads();

  // ---- main loop: one barrier per step ----
  for (int t = 0; t < TT; ++t){
    const int par = t & 1;
    const int ch  = (t >> 6) & 1;

    // MFMA: Y = W @ TH  (B-frags from th_lds[par], shared across both row-tiles)
    float4v acc0 = {0.f,0.f,0.f,0.f}, acc1 = {0.f,0.f,0.f,0.f};
    const char* tb = (const char*)&th_lds[par][0][0] + bi*528 + g*16;
    #pragma unroll
    for (int kt = 0; kt < 8; ++kt){
      short8v bf = *(const short8v*)(tb + kt*64);
      acc0 = __builtin_amdgcn_mfma_f32_16x16x32_bf16(afr[0][kt], bf, acc0, 0, 0, 0);
      acc1 = __builtin_amdgcn_mfma_f32_16x16x32_bf16(afr[1][kt], bf, acc1, 0, 0, 0);
    }

    float2 xv = *(const float2*)&x_lds[ch][t & 63][bi][0];
    float nv[8];
    if (par == 0){
      nv[0]=nzA0.x; nv[1]=nzA0.y; nv[2]=nzA0.z; nv[3]=nzA0.w;
      nv[4]=nzA1.x; nv[5]=nzA1.y; nv[6]=nzA1.z; nv[7]=nzA1.w;
    } else {
      nv[0]=nzB0.x; nv[1]=nzB0.y; nv[2]=nzB0.z; nv[3]=nzB0.w;
      nv[4]=nzB1.x; nv[5]=nzB1.y; nv[6]=nzB1.z; nv[7]=nzB1.w;
    }
    float ya[8] = {acc0[0],acc0[1],acc0[2],acc0[3], acc1[0],acc1[1],acc1[2],acc1[3]};

    float p0 = 0.f, p1 = 0.f;
    #pragma unroll
    for (int tau = 0; tau < 2; ++tau){
      uint32_t pk0 = 0u, pk1 = 0u;
      float hq[4];
      #pragma unroll
      for (int e = 0; e < 4; ++e){
        const int i8 = tau*4 + e;
        float u = fmaf(xv.x, wi0r[i8], xv.y*wi1r[i8]);
        float h = fmaf(0.25f, u + ya[i8], 0.75f*hr[i8]) + nv[i8];
        hr[i8] = h; hq[e] = h;
        p0 = fmaf(wo0r[i8], h, p0);
        p1 = fmaf(wo1r[i8], h, p1);
        float th = 1.0f - 2.0f/(__expf(2.0f*h) + 1.0f);
        uint32_t bb = (uint32_t)(uint16_t)f2bf(th);
        if (e < 2) pk0 |= bb << (16*e); else pk1 |= bb << (16*(e-2));
      }
      *(uint2*)((char*)&th_lds[par^1][0][0] + bi*528 + (w32 + tau*16 + g*4)*2) = make_uint2(pk0, pk1);
      *(float4*)&hst[par][bi][w32 + tau*16 + g*4] = make_float4(hq[0], hq[1], hq[2], hq[3]);
    }
    // outproj partial reduce across the 4 row-groups of this wave
    p0 += __shfl_xor(p0, 16, 64); p0 += __shfl_xor(p0, 32, 64);
    p1 += __shfl_xor(p1, 16, 64); p1 += __shfl_xor(p1, 32, 64);
    if (lane < 16){ opart[par][w][lane][0] = p0; opart[par][w][lane][1] = p1; }

    // noise prefetch for t+2 (into the set just consumed)
    if (t + 2 < TT){
      if (par == 0){
        nzA0 = *(const float4*)(nzb + (uint64_t)(t+2)*HB + w32 +      g*4);
        nzA1 = *(const float4*)(nzb + (uint64_t)(t+2)*HB + w32 + 16 + g*4);
      } else {
        nzB0 = *(const float4*)(nzb + (uint64_t)(t+2)*HB + w32 +      g*4);
        nzB1 = *(const float4*)(nzb + (uint64_t)(t+2)*HB + w32 + 16 + g*4);
      }
    }
    // x chunk refill (every 64 steps)
    if ((t & 63) == 0 && t + 64 < TT){
      const int xbi = tid >> 5, toff = (tid & 31)*2;
      float4 xc = *(const float4*)(input_signal + (uint64_t)(b0+xbi)*TT*2 + (t + 64 + toff)*2);
      x_lds[ch^1][toff  ][xbi][0] = xc.x; x_lds[ch^1][toff  ][xbi][1] = xc.y;
      x_lds[ch^1][toff+1][xbi][0] = xc.z; x_lds[ch^1][toff+1][xbi][1] = xc.w;
    }

    __syncthreads();                                   // the one barrier per step

    // flush h(t) (coalesced) + finalize o(t)
    {
      const int fbi = tid >> 5, r8 = (tid & 31)*8;
      float4 v0 = *(const float4*)&hst[par][fbi][r8];
      float4 v1 = *(const float4*)&hst[par][fbi][r8+4];
      float* dst = out + ((uint64_t)(b0+fbi)*TT + t)*HB + r8;
      *(float4*)dst = v0; *(float4*)(dst+4) = v1;
    }
    if (tid < 32){
      const int obi = tid >> 1, o = tid & 1;
      float s = 0.f;
      #pragma unroll
      for (int w8 = 0; w8 < 8; ++w8) s += opart[par][w8][obi][o];
      out[O1 + (uint64_t)(b0+obi)*TT*2 + t*2 + o] = s;
    }
  }

  // h_last from registers
  #pragma unroll
  for (int tau = 0; tau < 2; ++tau)
    #pragma unroll
    for (int e = 0; e < 4; ++e)
      out[O2 + (uint64_t)(b0+bi)*HB + w32 + tau*16 + g*4 + e] = hr[tau*4+e];
}

extern "C" void kernel_launch(void* const* d_in, const int* in_sizes, int n_in,
                              void* d_out, int out_size, void* d_ws, size_t ws_size,
                              hipStream_t stream) {
  const float* input_signal = (const float*)d_in[0];
  const float* hidden       = (const float*)d_in[1];
  const float* w_in         = (const float*)d_in[2];
  const float* w_out        = (const float*)d_in[3];
  const float* abs_w0       = (const float*)d_in[4];
  const float* w_sign       = (const float*)d_in[5];
  const float* is_con       = (const float*)d_in[6];
  float* out = (float*)d_out;

  noise_kernel<<<262144, 256, 0, stream>>>(out);
  rnn_kernel<<<16, 512, 0, stream>>>(input_signal, hidden, w_in, w_out,
                                     abs_w0, w_sign, is_con, out);
  check_kernel<<<1, 64, 0, stream>>>(out);
}